// Round 6
// baseline (129.511 us; speedup 1.0000x reference)
//
#include <hip/hip_runtime.h>

#define NUM_BINS 64
#define NPIX (256 * 256)
#define NIMG 16
#define HIST_SIZE (NUM_BINS * NUM_BINS)
#define OUT_ELEMS (NIMG * HIST_SIZE)

#define MM_BLOCKS 256
#define MM_THREADS 256

#define SUBS 48                      // hist blocks per image (ragged: 48*1408 > 65536)
#define H_BLOCKS (NIMG * SUBS)       // 768 = 3 blocks/CU
#define H_THREADS 256                // 4 waves
#define PPW 352                      // pixels per wave (11 steps of 32)
#define PPB (4 * PPW)                // 1408 pixel-slots per block
#define STEPS (PPW / 32)             // 11

#define TROWS 68                     // physical rows: bins -1..66 (phantom borders)
#define TCOLS 40                     // K=32 + 8 pad; 80B row stride
#define TSIZE (TROWS * TCOLS)        // USHORTS per operand tile (2720)
#define WREG (2 * TSIZE)             // USHORTS per wave region (A+B) = 5440
#define WREG_B (WREG * 2)            // BYTES per wave region = 10880

typedef __attribute__((ext_vector_type(8))) short bf16x8;
typedef __attribute__((ext_vector_type(4))) float f32x4;

__device__ __forceinline__ unsigned short f2bf(float f) {
    unsigned int u = __float_as_uint(f);
    unsigned int r = (u + 0x7FFFu + ((u >> 16) & 1u)) >> 16;  // RNE
    return (unsigned short)r;
}

// ================= K1: per-block min/max partials =================
__global__ __launch_bounds__(MM_THREADS) void minmax_part(
        const float4* __restrict__ ref4, const float4* __restrict__ tar4,
        float4* __restrict__ mmpart) {
    const int tid = blockIdx.x * MM_THREADS + threadIdx.x;
    const int stride = MM_BLOCKS * MM_THREADS;
    const int n4 = (NIMG * NPIX) / 4;
    float mnr = 3.0e38f, mxr = -3.0e38f, mnt = 3.0e38f, mxt = -3.0e38f;
    for (int i = tid; i < n4; i += stride) {
        float4 a = ref4[i];
        float4 b = tar4[i];
        mnr = fminf(mnr, fminf(fminf(a.x, a.y), fminf(a.z, a.w)));
        mxr = fmaxf(mxr, fmaxf(fmaxf(a.x, a.y), fmaxf(a.z, a.w)));
        mnt = fminf(mnt, fminf(fminf(b.x, b.y), fminf(b.z, b.w)));
        mxt = fmaxf(mxt, fmaxf(fmaxf(b.x, b.y), fmaxf(b.z, b.w)));
    }
    #pragma unroll
    for (int off = 32; off > 0; off >>= 1) {
        mnr = fminf(mnr, __shfl_down(mnr, off));
        mxr = fmaxf(mxr, __shfl_down(mxr, off));
        mnt = fminf(mnt, __shfl_down(mnt, off));
        mxt = fmaxf(mxt, __shfl_down(mxt, off));
    }
    __shared__ float s[4][MM_THREADS / 64];
    const int wave = threadIdx.x >> 6;
    if ((threadIdx.x & 63) == 0) {
        s[0][wave] = mnr; s[1][wave] = mxr; s[2][wave] = mnt; s[3][wave] = mxt;
    }
    __syncthreads();
    if (threadIdx.x == 0) {
        float a0 = s[0][0], a1 = s[1][0], a2 = s[2][0], a3 = s[3][0];
        #pragma unroll
        for (int w = 1; w < MM_THREADS / 64; ++w) {
            a0 = fminf(a0, s[0][w]);
            a1 = fmaxf(a1, s[1][w]);
            a2 = fminf(a2, s[2][w]);
            a3 = fmaxf(a3, s[3][w]);
        }
        mmpart[blockIdx.x] = make_float4(a0, a1, a2, a3);
    }
}

// ================= K2: MFMA joint histogram ==========================
// Intra-step order: weights(s) -> un-zero prev / write(s) -> fragment reads -> MFMA.
// (R4's read-before-write pipelining raced on the DS pipe — keep the RAW chain.)
__global__ __launch_bounds__(H_THREADS, 3) void hist_gemm(
        const float* __restrict__ ref, const float* __restrict__ tar,
        const float4* __restrict__ mmpart, float* __restrict__ part) {
    // tiles (K-loop) and cbuf (epilogue) are never live simultaneously: union them.
    __shared__ __align__(16) char smem[4 * WREG_B + 64];    // 43584 B -> 3 blocks/CU
    unsigned short* tiles = (unsigned short*)smem;
    float* cbuf = (float*)smem;                              // 64x65 floats = 16640 B
    float4* smm = (float4*)(smem + 4 * WREG_B);

    const int tid = threadIdx.x;
    const int wave = tid >> 6;
    const int lane = tid & 63;

    // ---- re-reduce the 256 min/max partials (one per thread) ----
    float4 v = mmpart[tid];
    #pragma unroll
    for (int off = 32; off > 0; off >>= 1) {
        v.x = fminf(v.x, __shfl_down(v.x, off));
        v.y = fmaxf(v.y, __shfl_down(v.y, off));
        v.z = fminf(v.z, __shfl_down(v.z, off));
        v.w = fmaxf(v.w, __shfl_down(v.w, off));
    }
    if (lane == 0) smm[wave] = v;

    // ---- zero this wave's tiles (per-wave private) ----
    unsigned short* wbase = tiles + wave * WREG;   // ushort units
    {
        uint4 z = {0u, 0u, 0u, 0u};
        uint4* p = (uint4*)wbase;
        #pragma unroll
        for (int i = 0; i < (WREG / 8 + 63) / 64; ++i) {
            int idx = lane + i * 64;
            if (idx < WREG / 8) p[idx] = z;
        }
    }
    __syncthreads();  // smm ready

    const float mn_r = fminf(fminf(smm[0].x, smm[1].x), fminf(smm[2].x, smm[3].x));
    const float mx_r = fmaxf(fmaxf(smm[0].y, smm[1].y), fmaxf(smm[2].y, smm[3].y));
    const float mn_t = fminf(fminf(smm[0].z, smm[1].z), fminf(smm[2].z, smm[3].z));
    const float mx_t = fmaxf(fmaxf(smm[0].w, smm[1].w), fmaxf(smm[2].w, smm[3].w));

    const bool isRef = (lane < 32);
    const float mn = isRef ? mn_r : mn_t;
    const float sc = isRef ? (64.0f / (mx_r - mn_r)) : (64.0f / (mx_t - mn_t));
    const float* __restrict__ src = isRef ? ref : tar;
    unsigned short* T = wbase + (isRef ? 0 : TSIZE);
    const int col = lane & 31;

    const int img = blockIdx.x / SUBS;
    const int sub = blockIdx.x % SUBS;
    const int poff0 = sub * PPB + wave * PPW + col;   // offset within image (may exceed NPIX)
    const int ibase = img * NPIX;

    f32x4 acc[4][4];
    #pragma unroll
    for (int a = 0; a < 4; ++a)
        #pragma unroll
        for (int b = 0; b < 4; ++b)
            acc[a][b] = (f32x4){0.f, 0.f, 0.f, 0.f};

    const unsigned short* aT = wbase;
    const unsigned short* bT = wbase + TSIZE;
    const int frow = (lane & 15) + 1;   // bin m -> physical row m+1
    const int fk = (lane >> 4) * 8;     // k slice within K=32

    int prev = 0;                        // row 0..3 are zeros; first un-zero is harmless
    float vcur = src[ibase + (poff0 < NPIX ? poff0 : 0)];
    for (int s = 0; s < STEPS; ++s) {
        // prefetch next step's pixel (VMEM, consumed next iteration)
        int offn = poff0 + (s + 1) * 32;
        float vnext = src[ibase + (offn < NPIX ? offn : 0)];

        // weights for step s
        float x = (vcur - mn) * sc;
        x = fminf(fmaxf(x, 0.0f), 64.0f);
        float fx = floorf(x);
        int ib = (int)fx;                // physical first row (= ir+1), 0..64
        float u = x - fx, um = 1.0f - u;
        float w0 = um * um * um * (1.0f / 6.0f);
        float w1 = (2.0f / 3.0f) - u * u + 0.5f * u * u * u;
        float w2 = (2.0f / 3.0f) - um * um + 0.5f * um * um * um;
        float w3 = u * u * u * (1.0f / 6.0f);
        unsigned short h0 = f2bf(w0), h1 = f2bf(w1), h2 = f2bf(w2), h3 = f2bf(w3);
        if (poff0 + s * 32 >= NPIX) { h0 = 0; h1 = 0; h2 = 0; h3 = 0; }  // ragged tail

        // un-zero previous step's cells, scatter new (RAW chain before the reads)
        unsigned short* tp = T + prev * TCOLS + col;
        tp[0] = 0; tp[TCOLS] = 0; tp[2 * TCOLS] = 0; tp[3 * TCOLS] = 0;
        unsigned short* tn = T + ib * TCOLS + col;
        tn[0] = h0; tn[TCOLS] = h1; tn[2 * TCOLS] = h2; tn[3 * TCOLS] = h3;
        prev = ib;

        // fragment reads (compiler inserts lgkmcnt against the writes above)
        bf16x8 af[4], bfr[4];
        #pragma unroll
        for (int mt = 0; mt < 4; ++mt)
            af[mt] = *(const bf16x8*)(aT + (mt * 16 + frow) * TCOLS + fk);
        #pragma unroll
        for (int nt = 0; nt < 4; ++nt)
            bfr[nt] = *(const bf16x8*)(bT + (nt * 16 + frow) * TCOLS + fk);

        #pragma unroll
        for (int mt = 0; mt < 4; ++mt)
            #pragma unroll
            for (int nt = 0; nt < 4; ++nt)
                acc[mt][nt] = __builtin_amdgcn_mfma_f32_16x16x32_bf16(
                    af[mt], bfr[nt], acc[mt][nt], 0, 0, 0);
        vcur = vnext;
    }

    // ---- epilogue: wave 0 stores C, waves 1-3 ds_add concurrently ----
    __syncthreads();   // all waves done with tiles; cbuf may now alias them
    const int crow0 = (lane >> 4) * 4;
    const int ccol = lane & 15;
    if (wave == 0) {
        #pragma unroll
        for (int mt = 0; mt < 4; ++mt)
            #pragma unroll
            for (int nt = 0; nt < 4; ++nt)
                #pragma unroll
                for (int r = 0; r < 4; ++r)
                    cbuf[(mt * 16 + crow0 + r) * 65 + nt * 16 + ccol] = acc[mt][nt][r];
    }
    __syncthreads();
    if (wave != 0) {
        #pragma unroll
        for (int mt = 0; mt < 4; ++mt)
            #pragma unroll
            for (int nt = 0; nt < 4; ++nt)
                #pragma unroll
                for (int r = 0; r < 4; ++r)
                    atomicAdd(&cbuf[(mt * 16 + crow0 + r) * 65 + nt * 16 + ccol],
                              acc[mt][nt][r]);
    }
    __syncthreads();
    float* po = part + (size_t)blockIdx.x * HIST_SIZE;
    for (int c = tid; c < HIST_SIZE; c += H_THREADS)
        po[c] = cbuf[(c >> 6) * 65 + (c & 63)];
}

// ================= K3: reduce SUBS partials per image, scale, store ============
__global__ __launch_bounds__(256) void reduce_k(
        const float* __restrict__ part, float* __restrict__ out) {
    const int i = blockIdx.x * 256 + threadIdx.x;
    const int img = i >> 12;
    const int c = i & (HIST_SIZE - 1);
    const float* p = part + (size_t)(img * SUBS) * HIST_SIZE + c;
    float sum = 0.0f;
    #pragma unroll
    for (int s = 0; s < SUBS; ++s) sum += p[(size_t)s * HIST_SIZE];
    out[i] = sum * 4096.0f;  // 1/EPS^2
}

extern "C" void kernel_launch(void* const* d_in, const int* in_sizes, int n_in,
                              void* d_out, int out_size, void* d_ws, size_t ws_size,
                              hipStream_t stream) {
    const float* ref = (const float*)d_in[0];
    const float* tar = (const float*)d_in[1];
    float* out = (float*)d_out;

    float4* mmpart = (float4*)d_ws;
    float* part = (float*)((char*)d_ws + MM_BLOCKS * sizeof(float4));

    minmax_part<<<MM_BLOCKS, MM_THREADS, 0, stream>>>(
        (const float4*)ref, (const float4*)tar, mmpart);
    hist_gemm<<<H_BLOCKS, H_THREADS, 0, stream>>>(ref, tar, mmpart, part);
    reduce_k<<<OUT_ELEMS / 256, 256, 0, stream>>>(part, out);
}

// Round 7
// 84.347 us; speedup vs baseline: 1.5355x; 1.5355x over previous
//
#include <hip/hip_runtime.h>

#define NUM_BINS 64
#define NPIX (256 * 256)
#define NIMG 16
#define HIST_SIZE (NUM_BINS * NUM_BINS)
#define OUT_ELEMS (NIMG * HIST_SIZE)

#define MM_BLOCKS 256
#define MM_THREADS 256

#define SUBS 32                      // hist blocks per image
#define H_BLOCKS (NIMG * SUBS)       // 512
#define H_THREADS 256                // 4 waves
#define PPB (NPIX / SUBS)            // 2048 px per block
#define PPW (PPB / 4)                // 512 px per wave
#define STEPS (PPW / 32)             // 16 k-steps of 32 px

#define TROWS 68                     // 64 bins + phantom borders (never read as bins)
#define TCOLS 40                     // K=32 + 8 pad; 80B row stride, 16B-aligned b128
#define TSIZE (TROWS * TCOLS)        // ushorts per matrix tile
#define WREG (2 * TSIZE)             // ushorts per wave region (A + B)

typedef __attribute__((ext_vector_type(8))) short bf16x8;
typedef __attribute__((ext_vector_type(4))) float f32x4;

__device__ __forceinline__ unsigned short f2bf(float f) {
    unsigned int u = __float_as_uint(f);
    unsigned int r = (u + 0x7FFFu + ((u >> 16) & 1u)) >> 16;  // RNE
    return (unsigned short)r;
}

// ================= K1: per-block min/max partials =================
__global__ __launch_bounds__(MM_THREADS) void minmax_part(
        const float4* __restrict__ ref4, const float4* __restrict__ tar4,
        float4* __restrict__ mmpart) {
    const int tid = blockIdx.x * MM_THREADS + threadIdx.x;
    const int stride = MM_BLOCKS * MM_THREADS;
    const int n4 = (NIMG * NPIX) / 4;
    float mnr = 3.0e38f, mxr = -3.0e38f, mnt = 3.0e38f, mxt = -3.0e38f;
    for (int i = tid; i < n4; i += stride) {
        float4 a = ref4[i];
        float4 b = tar4[i];
        mnr = fminf(mnr, fminf(fminf(a.x, a.y), fminf(a.z, a.w)));
        mxr = fmaxf(mxr, fmaxf(fmaxf(a.x, a.y), fmaxf(a.z, a.w)));
        mnt = fminf(mnt, fminf(fminf(b.x, b.y), fminf(b.z, b.w)));
        mxt = fmaxf(mxt, fmaxf(fmaxf(b.x, b.y), fmaxf(b.z, b.w)));
    }
    #pragma unroll
    for (int off = 32; off > 0; off >>= 1) {
        mnr = fminf(mnr, __shfl_down(mnr, off));
        mxr = fmaxf(mxr, __shfl_down(mxr, off));
        mnt = fminf(mnt, __shfl_down(mnt, off));
        mxt = fmaxf(mxt, __shfl_down(mxt, off));
    }
    __shared__ float s[4][MM_THREADS / 64];
    const int wave = threadIdx.x >> 6;
    if ((threadIdx.x & 63) == 0) {
        s[0][wave] = mnr; s[1][wave] = mxr; s[2][wave] = mnt; s[3][wave] = mxt;
    }
    __syncthreads();
    if (threadIdx.x == 0) {
        float a0 = s[0][0], a1 = s[1][0], a2 = s[2][0], a3 = s[3][0];
        #pragma unroll
        for (int w = 1; w < MM_THREADS / 64; ++w) {
            a0 = fminf(a0, s[0][w]);
            a1 = fmaxf(a1, s[1][w]);
            a2 = fminf(a2, s[2][w]);
            a3 = fmaxf(a3, s[3][w]);
        }
        mmpart[blockIdx.x] = make_float4(a0, a1, a2, a3);
    }
}

// ================= K2: MFMA joint histogram ==========================
// Per wave: private A/B operand tiles in LDS; lane<32 builds A (ref),
// lane>=32 builds B (tar) for the same 32 pixels. 16 MFMAs per 32 px.
__global__ __launch_bounds__(H_THREADS) void hist_gemm(
        const float* __restrict__ ref, const float* __restrict__ tar,
        const float4* __restrict__ mmpart, float* __restrict__ part) {
    __shared__ unsigned short tiles[4 * WREG];     // 43520 B
    __shared__ float cbuf[64 * 65];                // 16640 B (stride 65)
    __shared__ float4 smm[4];

    const int tid = threadIdx.x;
    const int wave = tid >> 6;
    const int lane = tid & 63;

    // ---- re-reduce the 256 min/max partials (one per thread) ----
    float4 v = mmpart[tid];
    #pragma unroll
    for (int off = 32; off > 0; off >>= 1) {
        v.x = fminf(v.x, __shfl_down(v.x, off));
        v.y = fmaxf(v.y, __shfl_down(v.y, off));
        v.z = fminf(v.z, __shfl_down(v.z, off));
        v.w = fmaxf(v.w, __shfl_down(v.w, off));
    }
    if (lane == 0) smm[wave] = v;

    // ---- zero this wave's tiles (per-wave private: no barrier needed) ----
    unsigned short* wbase = tiles + wave * WREG;
    {
        uint4 z = {0u, 0u, 0u, 0u};
        uint4* p = (uint4*)wbase;
        #pragma unroll
        for (int i = 0; i < (WREG / 8 + 63) / 64; ++i) {
            int idx = lane + i * 64;
            if (idx < WREG / 8) p[idx] = z;
        }
    }
    __syncthreads();  // smm ready

    const float mn_r = fminf(fminf(smm[0].x, smm[1].x), fminf(smm[2].x, smm[3].x));
    const float mx_r = fmaxf(fmaxf(smm[0].y, smm[1].y), fmaxf(smm[2].y, smm[3].y));
    const float mn_t = fminf(fminf(smm[0].z, smm[1].z), fminf(smm[2].z, smm[3].z));
    const float mx_t = fmaxf(fmaxf(smm[0].w, smm[1].w), fmaxf(smm[2].w, smm[3].w));

    const bool isRef = (lane < 32);
    const float mn = isRef ? mn_r : mn_t;
    const float sc = isRef ? (64.0f / (mx_r - mn_r)) : (64.0f / (mx_t - mn_t));
    const float* __restrict__ src = isRef ? ref : tar;
    unsigned short* T = wbase + (isRef ? 0 : TSIZE);
    const int col = lane & 31;

    const int img = blockIdx.x / SUBS;
    const int sub = blockIdx.x % SUBS;
    const int pbase = img * NPIX + sub * PPB + wave * PPW + col;

    f32x4 acc[4][4];
    #pragma unroll
    for (int a = 0; a < 4; ++a)
        #pragma unroll
        for (int b = 0; b < 4; ++b)
            acc[a][b] = (f32x4){0.f, 0.f, 0.f, 0.f};

    const unsigned short* aT = wbase;
    const unsigned short* bT = wbase + TSIZE;
    const int frow = (lane & 15) + 1;   // bin m -> physical row m+1
    const int fk = (lane >> 4) * 8;     // k slice within K=32

    int prev = 0;
    float vcur = src[pbase];
    for (int s = 0; s < STEPS; ++s) {
        float vnext = (s + 1 < STEPS) ? src[pbase + (s + 1) * 32] : 0.0f;
        float x = (vcur - mn) * sc;              // in [0, 64]
        float fx = floorf(x);
        int ib = (int)fx;                        // physical first row (= ir+1), 0..64
        float u = x - fx;
        float um = 1.0f - u;
        float w0 = um * um * um * (1.0f / 6.0f);
        float w1 = (2.0f / 3.0f) - u * u + 0.5f * u * u * u;
        float w2 = (2.0f / 3.0f) - um * um + 0.5f * um * um * um;
        float w3 = u * u * u * (1.0f / 6.0f);
        unsigned short h0 = f2bf(w0), h1 = f2bf(w1), h2 = f2bf(w2), h3 = f2bf(w3);

        // un-zero previous step's 4 cells, then scatter the new 4 (DS in-order per wave)
        unsigned short* tp = T + prev * TCOLS + col;
        tp[0] = 0; tp[TCOLS] = 0; tp[2 * TCOLS] = 0; tp[3 * TCOLS] = 0;
        unsigned short* tn = T + ib * TCOLS + col;
        tn[0] = h0; tn[TCOLS] = h1; tn[2 * TCOLS] = h2; tn[3 * TCOLS] = h3;
        prev = ib;

        bf16x8 af[4], bfr[4];
        #pragma unroll
        for (int mt = 0; mt < 4; ++mt)
            af[mt] = *(const bf16x8*)(aT + (mt * 16 + frow) * TCOLS + fk);
        #pragma unroll
        for (int nt = 0; nt < 4; ++nt)
            bfr[nt] = *(const bf16x8*)(bT + (nt * 16 + frow) * TCOLS + fk);
        #pragma unroll
        for (int mt = 0; mt < 4; ++mt)
            #pragma unroll
            for (int nt = 0; nt < 4; ++nt)
                acc[mt][nt] = __builtin_amdgcn_mfma_f32_16x16x32_bf16(
                    af[mt], bfr[nt], acc[mt][nt], 0, 0, 0);
        vcur = vnext;
    }

    // ---- combine the 4 waves' C into cbuf (C/D: col=lane&15, row=quad*4+reg) ----
    const int crow0 = (lane >> 4) * 4;
    const int ccol = lane & 15;
    for (int ph = 0; ph < 4; ++ph) {
        if (wave == ph) {
            #pragma unroll
            for (int mt = 0; mt < 4; ++mt)
                #pragma unroll
                for (int nt = 0; nt < 4; ++nt)
                    #pragma unroll
                    for (int r = 0; r < 4; ++r) {
                        int idx = (mt * 16 + crow0 + r) * 65 + nt * 16 + ccol;
                        if (ph == 0) cbuf[idx] = acc[mt][nt][r];
                        else cbuf[idx] += acc[mt][nt][r];
                    }
        }
        __syncthreads();
    }
    float* po = part + (size_t)blockIdx.x * HIST_SIZE;
    for (int c = tid; c < HIST_SIZE; c += H_THREADS)
        po[c] = cbuf[(c >> 6) * 65 + (c & 63)];
}

// ================= K3: reduce SUBS partials per image, scale, store ============
__global__ __launch_bounds__(256) void reduce_k(
        const float* __restrict__ part, float* __restrict__ out) {
    const int i = blockIdx.x * 256 + threadIdx.x;
    const int img = i >> 12;
    const int c = i & (HIST_SIZE - 1);
    const float* p = part + (size_t)(img * SUBS) * HIST_SIZE + c;
    float sum = 0.0f;
    #pragma unroll
    for (int s = 0; s < SUBS; ++s) sum += p[(size_t)s * HIST_SIZE];
    out[i] = sum * 4096.0f;  // 1/EPS^2
}

extern "C" void kernel_launch(void* const* d_in, const int* in_sizes, int n_in,
                              void* d_out, int out_size, void* d_ws, size_t ws_size,
                              hipStream_t stream) {
    const float* ref = (const float*)d_in[0];
    const float* tar = (const float*)d_in[1];
    float* out = (float*)d_out;

    float4* mmpart = (float4*)d_ws;
    float* part = (float*)((char*)d_ws + MM_BLOCKS * sizeof(float4));

    minmax_part<<<MM_BLOCKS, MM_THREADS, 0, stream>>>(
        (const float4*)ref, (const float4*)tar, mmpart);
    hist_gemm<<<H_BLOCKS, H_THREADS, 0, stream>>>(ref, tar, mmpart, part);
    reduce_k<<<OUT_ELEMS / 256, 256, 0, stream>>>(part, out);
}